// Round 1
// baseline (338.780 us; speedup 1.0000x reference)
//
#include <hip/hip_runtime.h>

// VectorQuantizer: latents (16,128,64,64) f32, codebook (1024,128) f32.
// out[b,d,h,w] = codebook[argmin_k fl(fl(x2 - 2*dot(x,e_k)) + e2_k)][d]
//
// MFMA bf16 scoring + exact fp32 rescue (numerics identical to prior rounds):
//  phase 1: 16x16x32 bf16 MFMA scores (fp32 acc) -> per-px bf16 min.
//  phase 2: recompute scores; candidates = { k : S_bf <= min + 2*M[px] },
//           M = 2e-4*sqrt(x2)+1.5e-4 (Cauchy-Schwarz bound, input spec).
//  rescue:  exact fp32 serial ascending-d fmaf chain on ~1.8 cands/px;
//           lex (t3,k) u64 atomicMin keeps np first-index tie-break.
//
// Round-4 changes (latency/occupancy round):
//  - prep: 32 blocks x 256 thr, coalesced float4 convert-from-registers
//    (was 8 blocks of uncoalesced scalar loads ~ 60us). e2 chains unchanged.
//  - LDS 43.5->40KB (bfminw aliased onto cand, disjoint lifetimes across
//    a barrier; cand 2048->1728) + launch_bounds(256,4): 4 blocks/CU ->
//    whole 1024-block grid resident, no 1.33-fill tail.
//  - nontemporal latents loads / out stores: stop evicting the L2-resident
//    bf16 codebook (each block re-reads 512KB of it; 512MB aggregate).
//  - dual-buffered B-frag prefetch (2 codes/iter); per-iter e2 scalar load
//    replaces the runtime-indexed e2r[16] array (scratch under unroll 1).

typedef __attribute__((ext_vector_type(8))) short short8;
typedef __attribute__((ext_vector_type(4))) float f32x4;

#define VQ_D 128
#define VQ_K 1024
#define VQ_HW 4096
#define CAND_CAP 1728

__device__ inline unsigned short f2bf(float f) {   // RNE fp32->bf16
    unsigned u = __float_as_uint(f);
    return (unsigned short)((u + 0x7FFFu + ((u >> 16) & 1u)) >> 16);
}

__global__ __launch_bounds__(256)
void vq_prep_kernel(const float* __restrict__ cb, unsigned short* __restrict__ cbbf,
                    float* __restrict__ e2) {
    const int tid = threadIdx.x;
    const int k0  = blockIdx.x << 5;                 // 32 codes/block, grid=32
    const float4* s4 = (const float4*)(cb + (size_t)k0 * VQ_D);
    ushort4* d4 = (ushort4*)(cbbf + (size_t)k0 * VQ_D);
    #pragma unroll
    for (int i = 0; i < 4; ++i) {                    // 1024 float4 per block
        const int idx = i * 256 + tid;
        const float4 v = s4[idx];
        ushort4 p;
        p.x = f2bf(v.x); p.y = f2bf(v.y); p.z = f2bf(v.z); p.w = f2bf(v.w);
        d4[idx] = p;
    }
    if (tid < 32) {                                  // serial chain, same order
        const float* crow = cb + (size_t)(k0 + tid) * VQ_D;
        float s = 0.f;
        #pragma unroll
        for (int d = 0; d < VQ_D; ++d) s = fmaf(crow[d], crow[d], s);
        e2[k0 + tid] = s;
    }
}

#define VQ_LDB(Bdst, c_)                                                         \
    {                                                                            \
        _Pragma("unroll")                                                        \
        for (int t = 0; t < 4; ++t)                                              \
            Bdst[t] = *(const short8*)(bbase + (size_t)(c_) * 16 * VQ_D + t * 32); \
    }

#define VQ_P1(Bv, c_)                                                            \
    {                                                                            \
        const float e2c = e2g[(c_) * 16];                                        \
        f32x4 Cm[4] = {{0.f,0.f,0.f,0.f},{0.f,0.f,0.f,0.f},                      \
                       {0.f,0.f,0.f,0.f},{0.f,0.f,0.f,0.f}};                     \
        _Pragma("unroll")                                                        \
        for (int t = 0; t < 4; ++t)                                              \
            _Pragma("unroll")                                                    \
            for (int p = 0; p < 4; ++p)                                          \
                Cm[p] = __builtin_amdgcn_mfma_f32_16x16x32_bf16(                 \
                            A[p * 4 + t], Bv[t], Cm[p], 0, 0, 0);                \
        _Pragma("unroll")                                                        \
        for (int p = 0; p < 4; ++p)                                              \
            _Pragma("unroll")                                                    \
            for (int r = 0; r < 4; ++r) {                                        \
                const float s = (x2r[p * 4 + r] - 2.0f * Cm[p][r]) + e2c;        \
                bmin[p * 4 + r] = fminf(bmin[p * 4 + r], s);                     \
            }                                                                    \
    }

#define VQ_P2(Bv, c_)                                                            \
    {                                                                            \
        const float e2c = e2g[(c_) * 16];                                        \
        f32x4 Cm[4] = {{0.f,0.f,0.f,0.f},{0.f,0.f,0.f,0.f},                      \
                       {0.f,0.f,0.f,0.f},{0.f,0.f,0.f,0.f}};                     \
        _Pragma("unroll")                                                        \
        for (int t = 0; t < 4; ++t)                                              \
            _Pragma("unroll")                                                    \
            for (int p = 0; p < 4; ++p)                                          \
                Cm[p] = __builtin_amdgcn_mfma_f32_16x16x32_bf16(                 \
                            A[p * 4 + t], Bv[t], Cm[p], 0, 0, 0);                \
        _Pragma("unroll")                                                        \
        for (int p = 0; p < 4; ++p)                                              \
            _Pragma("unroll")                                                    \
            for (int r = 0; r < 4; ++r) {                                        \
                const float s = (x2r[p * 4 + r] - 2.0f * Cm[p][r]) + e2c;        \
                if (s <= thr[p * 4 + r]) {                                       \
                    const int idx = atomicAdd(&ncand, 1);                        \
                    if (idx < CAND_CAP) {                                        \
                        const int px   = p * 16 + quad * 4 + r;                  \
                        const int code = wave * 256 + (c_) * 16 + mm;            \
                        cand[idx] = ((unsigned)px << 16) | (unsigned)code;       \
                    }                                                            \
                }                                                                \
            }                                                                    \
    }

__global__ __launch_bounds__(256, 4)
void vq_main_kernel(const float* __restrict__ latents,
                    const float* __restrict__ cb,
                    const unsigned short* __restrict__ cbbf,
                    const float* __restrict__ e2,
                    float* __restrict__ out) {
    __shared__ __align__(16) float xl[VQ_D * 64];       // [d][px] 32 KB
    __shared__ float x2s[64];
    __shared__ float threshs[64];
    __shared__ unsigned long long fkey[64];
    __shared__ __align__(16) unsigned int cand[CAND_CAP];
    __shared__ int ncand;
    // bfminw lives in cand's storage: last read before the barrier that
    // precedes the first cand write (disjoint lifetimes).
    float (*bfminw)[64] = (float (*)[64])cand;

    const int tid  = threadIdx.x;
    const int lane = tid & 63;
    const int wave = __builtin_amdgcn_readfirstlane(tid >> 6);
    const int quad = lane >> 4;
    const int mm   = lane & 15;
    const int blk  = blockIdx.x;
    const int b    = blk >> 6;
    const int hw0  = (blk & 63) << 6;

    const float* xg = latents + (size_t)b * VQ_D * VQ_HW + hw0;

    // ---- stage x tile [d][px], coalesced nontemporal float4 ----
    {
        const int px4 = (tid & 15) << 2;
        const int db  = (tid >> 4) << 3;
        #pragma unroll
        for (int i = 0; i < 8; ++i) {
            const int d = db + i;
            const f32x4 v = __builtin_nontemporal_load(
                (const f32x4*)(xg + (size_t)d * VQ_HW + px4));
            *(f32x4*)(xl + d * 64 + px4) = v;
        }
    }
    if (tid == 0) ncand = 0;
    if (tid < 64) fkey[tid] = ~0ULL;
    __syncthreads();

    // x2 per px: serial ascending-d chain (unchanged numerics)
    if (tid < 64) {
        float s = 0.f;
        #pragma unroll
        for (int d = 0; d < VQ_D; ++d) {
            const float v = xl[d * 64 + tid];
            s = fmaf(v, v, s);
        }
        x2s[tid] = s;
    }

    // ---- A fragments (held in VGPRs all sweep): px=p*16+mm, d=t*32+quad*8+j
    short8 A[16];
    #pragma unroll
    for (int p = 0; p < 4; ++p) {
        #pragma unroll
        for (int t = 0; t < 4; ++t) {
            short8 a;
            #pragma unroll
            for (int j = 0; j < 8; ++j) {
                const float v = xl[(t * 32 + quad * 8 + j) * 64 + p * 16 + mm];
                a[j] = (short)f2bf(v);
            }
            A[p * 4 + t] = a;
        }
    }

    const float* e2g = e2 + wave * 256 + mm;

    __syncthreads();   // x2s ready

    float x2r[16];
    #pragma unroll
    for (int p = 0; p < 4; ++p)
        #pragma unroll
        for (int r = 0; r < 4; ++r)
            x2r[p * 4 + r] = x2s[p * 16 + quad * 4 + r];

    // B-frag base: code = wave*256 + c*16 + mm, d = t*32 + quad*8 + j
    const unsigned short* bbase = cbbf + (size_t)(wave * 256 + mm) * VQ_D + quad * 8;

    // ---- phase 1: bf16 score min per px (dual-buffered B prefetch) ----
    float bmin[16];
    #pragma unroll
    for (int i = 0; i < 16; ++i) bmin[i] = 1e30f;

    {
        short8 Ba[4], Bb[4];
        VQ_LDB(Ba, 0);
        #pragma unroll 1
        for (int cc = 0; cc < 8; ++cc) {
            const int c0 = cc * 2;
            VQ_LDB(Bb, c0 + 1);
            VQ_P1(Ba, c0);
            if (cc < 7) VQ_LDB(Ba, c0 + 2);
            VQ_P1(Bb, c0 + 1);
        }
    }

    // reduce min across the 16 lanes of each quad-group (code dimension)
    #pragma unroll
    for (int i = 0; i < 16; ++i) {
        float v = bmin[i];
        v = fminf(v, __shfl_xor(v, 1));
        v = fminf(v, __shfl_xor(v, 2));
        v = fminf(v, __shfl_xor(v, 4));
        v = fminf(v, __shfl_xor(v, 8));
        bmin[i] = v;
    }
    if (mm == 0) {
        #pragma unroll
        for (int p = 0; p < 4; ++p)
            #pragma unroll
            for (int r = 0; r < 4; ++r)
                bfminw[wave][p * 16 + quad * 4 + r] = bmin[p * 4 + r];
    }
    __syncthreads();
    if (tid < 64) {
        const float mn = fminf(fminf(bfminw[0][tid], bfminw[1][tid]),
                               fminf(bfminw[2][tid], bfminw[3][tid]));
        const float M = 2.0e-4f * sqrtf(x2s[tid]) + 1.5e-4f;
        threshs[tid] = mn + 2.0f * M;
    }
    __syncthreads();   // after this barrier bfminw is dead; cand may be written

    float thr[16];
    #pragma unroll
    for (int p = 0; p < 4; ++p)
        #pragma unroll
        for (int r = 0; r < 4; ++r)
            thr[p * 4 + r] = threshs[p * 16 + quad * 4 + r];

    // ---- phase 2: recompute, collect candidates ----
    {
        short8 Ba[4], Bb[4];
        VQ_LDB(Ba, 0);
        #pragma unroll 1
        for (int cc = 0; cc < 8; ++cc) {
            const int c0 = cc * 2;
            VQ_LDB(Bb, c0 + 1);
            VQ_P2(Ba, c0);
            if (cc < 7) VQ_LDB(Ba, c0 + 2);
            VQ_P2(Bb, c0 + 1);
        }
    }
    __syncthreads();

    // ---- rescue: exact fp32 serial chain on candidates, one per lane ----
    const int nc = ncand < CAND_CAP ? ncand : CAND_CAP;
    for (int i = tid; i < nc; i += 256) {
        const unsigned pc = cand[i];
        const int px = (int)(pc >> 16);
        const int k  = (int)(pc & 0xFFFFu);
        const float* crow = cb + (size_t)k * VQ_D;
        float dot = 0.f;
        #pragma unroll
        for (int q = 0; q < 32; ++q) {
            const float4 cv = *(const float4*)(crow + q * 4);
            dot = fmaf(xl[(q * 4 + 0) * 64 + px], cv.x, dot);
            dot = fmaf(xl[(q * 4 + 1) * 64 + px], cv.y, dot);
            dot = fmaf(xl[(q * 4 + 2) * 64 + px], cv.z, dot);
            dot = fmaf(xl[(q * 4 + 3) * 64 + px], cv.w, dot);
        }
        const float t3 = (x2s[px] - 2.0f * dot) + e2[k];
        const unsigned long long key =
            ((unsigned long long)__float_as_uint(t3) << 32) | (unsigned)k;
        atomicMin(&fkey[px], key);
    }
    __syncthreads();

    // ---- writeback: vectorized codebook reads, nontemporal out stores ----
    {
        const int px = tid & 63;
        const int dh = tid >> 6;
        const int fb = (int)(fkey[px] & 0xFFFFFFFFULL);
        const float* crow = cb + (size_t)fb * VQ_D + dh * 32;
        float* og = out + (size_t)b * VQ_D * VQ_HW + hw0;
        #pragma unroll
        for (int j = 0; j < 8; ++j) {
            const float4 cv = *(const float4*)(crow + j * 4);
            const int d = dh * 32 + j * 4;
            __builtin_nontemporal_store(cv.x, &og[(size_t)(d + 0) * VQ_HW + px]);
            __builtin_nontemporal_store(cv.y, &og[(size_t)(d + 1) * VQ_HW + px]);
            __builtin_nontemporal_store(cv.z, &og[(size_t)(d + 2) * VQ_HW + px]);
            __builtin_nontemporal_store(cv.w, &og[(size_t)(d + 3) * VQ_HW + px]);
        }
    }
}

extern "C" void kernel_launch(void* const* d_in, const int* in_sizes, int n_in,
                              void* d_out, int out_size, void* d_ws, size_t ws_size,
                              hipStream_t stream) {
    const float* latents = (const float*)d_in[0];
    const float* cb      = (const float*)d_in[1];
    unsigned short* cbbf = (unsigned short*)d_ws;              // 256 KB
    float* e2            = (float*)((char*)d_ws + 262144);     // 4 KB
    float* out           = (float*)d_out;

    vq_prep_kernel<<<dim3(32), dim3(256), 0, stream>>>(cb, cbbf, e2);
    vq_main_kernel<<<dim3(1024), dim3(256), 0, stream>>>(latents, cb, cbbf, e2, out);
}

// Round 2
// 172.028 us; speedup vs baseline: 1.9693x; 1.9693x over previous
//
#include <hip/hip_runtime.h>

// VectorQuantizer: latents (16,128,64,64) f32, codebook (1024,128) f32.
// out[b,d,h,w] = codebook[argmin_k fl(fl(x2 - 2*dot(x,e_k)) + e2_k)][d]
//
// MFMA bf16 scoring + exact fp32 rescue (numerics identical to prior rounds):
//  phase 1: 16x16x32 bf16 MFMA scores (fp32 acc) -> per-px bf16 min.
//  phase 2: recompute scores; candidates = { k : S_bf <= min + 2*M[px] },
//           M = 2e-4*sqrt(x2)+1.5e-4 (Cauchy-Schwarz bound, input spec).
//  rescue:  exact fp32 serial ascending-d fmaf chain on ~1.8 cands/px;
//           lex (t3,k) u64 atomicMin keeps np first-index tie-break.
//
// Round-5 (post-mortem of the launch_bounds(256,4) disaster):
//  - REVERTED the occupancy floor: (256,4) forced VGPR 84->64, spilling the
//    64-VGPR A-fragment array to scratch (FETCH 25MB->737MB, main 126->275us).
//    Plain __launch_bounds__(256): proven 84-VGPR allocation, no spills.
//  - KEPT: fast prep (32 blocks, coalesced float4 convert; was 8-block
//    uncoalesced scalar ~60us), LDS 43.5->40KB (bfminw aliased onto cand,
//    disjoint lifetimes) -> 4 blocks/CU from LDS+VGPR naturally, whole
//    1024-block grid resident; per-iter scalar e2 load (kills runtime-indexed
//    e2r[16] scratch array); vectorized writeback; nontemporal OUT stores.
//  - DROPPED: nontemporal latents loads (round-0 FETCH=25MB < latents size
//    proves L3 was serving them; nt forfeits that), dual-buffered B prefetch
//    (register pressure risk; 16 waves/CU TLP hides B-load latency instead).

typedef __attribute__((ext_vector_type(8))) short short8;
typedef __attribute__((ext_vector_type(4))) float f32x4;

#define VQ_D 128
#define VQ_K 1024
#define VQ_HW 4096
#define CAND_CAP 1728

__device__ inline unsigned short f2bf(float f) {   // RNE fp32->bf16
    unsigned u = __float_as_uint(f);
    return (unsigned short)((u + 0x7FFFu + ((u >> 16) & 1u)) >> 16);
}

__global__ __launch_bounds__(256)
void vq_prep_kernel(const float* __restrict__ cb, unsigned short* __restrict__ cbbf,
                    float* __restrict__ e2) {
    const int tid = threadIdx.x;
    const int k0  = blockIdx.x << 5;                 // 32 codes/block, grid=32
    const float4* s4 = (const float4*)(cb + (size_t)k0 * VQ_D);
    ushort4* d4 = (ushort4*)(cbbf + (size_t)k0 * VQ_D);
    #pragma unroll
    for (int i = 0; i < 4; ++i) {                    // 1024 float4 per block
        const int idx = i * 256 + tid;
        const float4 v = s4[idx];
        ushort4 p;
        p.x = f2bf(v.x); p.y = f2bf(v.y); p.z = f2bf(v.z); p.w = f2bf(v.w);
        d4[idx] = p;
    }
    if (tid < 32) {                                  // serial chain, same order
        const float* crow = cb + (size_t)(k0 + tid) * VQ_D;
        float s = 0.f;
        #pragma unroll
        for (int d = 0; d < VQ_D; ++d) s = fmaf(crow[d], crow[d], s);
        e2[k0 + tid] = s;
    }
}

__global__ __launch_bounds__(256)
void vq_main_kernel(const float* __restrict__ latents,
                    const float* __restrict__ cb,
                    const unsigned short* __restrict__ cbbf,
                    const float* __restrict__ e2,
                    float* __restrict__ out) {
    __shared__ __align__(16) float xl[VQ_D * 64];       // [d][px] 32 KB
    __shared__ float x2s[64];
    __shared__ float threshs[64];
    __shared__ unsigned long long fkey[64];
    __shared__ __align__(16) unsigned int cand[CAND_CAP];
    __shared__ int ncand;
    // bfminw lives in cand's storage: last read is before the barrier that
    // precedes the first cand write (disjoint lifetimes).
    float (*bfminw)[64] = (float (*)[64])cand;

    const int tid  = threadIdx.x;
    const int lane = tid & 63;
    const int wave = __builtin_amdgcn_readfirstlane(tid >> 6);
    const int quad = lane >> 4;
    const int mm   = lane & 15;
    const int blk  = blockIdx.x;
    const int b    = blk >> 6;
    const int hw0  = (blk & 63) << 6;

    const float* xg = latents + (size_t)b * VQ_D * VQ_HW + hw0;

    // ---- stage x tile [d][px], coalesced float4 (L3-served across iters) ----
    {
        const int px4 = (tid & 15) << 2;
        const int db  = (tid >> 4) << 3;
        #pragma unroll
        for (int i = 0; i < 8; ++i) {
            const int d = db + i;
            *(float4*)(xl + d * 64 + px4) =
                *(const float4*)(xg + (size_t)d * VQ_HW + px4);
        }
    }
    if (tid == 0) ncand = 0;
    if (tid < 64) fkey[tid] = ~0ULL;
    __syncthreads();

    // x2 per px: serial ascending-d chain (unchanged numerics)
    if (tid < 64) {
        float s = 0.f;
        #pragma unroll
        for (int d = 0; d < VQ_D; ++d) {
            const float v = xl[d * 64 + tid];
            s = fmaf(v, v, s);
        }
        x2s[tid] = s;
    }

    // ---- A fragments (held in VGPRs all sweep): px=p*16+mm, d=t*32+quad*8+j
    short8 A[16];
    #pragma unroll
    for (int p = 0; p < 4; ++p) {
        #pragma unroll
        for (int t = 0; t < 4; ++t) {
            short8 a;
            #pragma unroll
            for (int j = 0; j < 8; ++j) {
                const float v = xl[(t * 32 + quad * 8 + j) * 64 + p * 16 + mm];
                a[j] = (short)f2bf(v);
            }
            A[p * 4 + t] = a;
        }
    }

    const float* e2g = e2 + wave * 256 + mm;   // e2 for code c*16: e2g[c*16]

    __syncthreads();   // x2s ready

    float x2r[16];
    #pragma unroll
    for (int p = 0; p < 4; ++p)
        #pragma unroll
        for (int r = 0; r < 4; ++r)
            x2r[p * 4 + r] = x2s[p * 16 + quad * 4 + r];

    // B-frag base: code = wave*256 + c*16 + mm, d = t*32 + quad*8 + j
    const unsigned short* bbase = cbbf + (size_t)(wave * 256 + mm) * VQ_D + quad * 8;

    // ---- phase 1: bf16 score min per px ----
    float bmin[16];
    #pragma unroll
    for (int i = 0; i < 16; ++i) bmin[i] = 1e30f;

    #pragma unroll 1
    for (int c = 0; c < 16; ++c) {
        short8 B[4];
        #pragma unroll
        for (int t = 0; t < 4; ++t)
            B[t] = *(const short8*)(bbase + (size_t)c * 16 * VQ_D + t * 32);
        const float e2c = e2g[c * 16];
        f32x4 C[4] = {{0.f,0.f,0.f,0.f},{0.f,0.f,0.f,0.f},
                      {0.f,0.f,0.f,0.f},{0.f,0.f,0.f,0.f}};
        #pragma unroll
        for (int t = 0; t < 4; ++t)
            #pragma unroll
            for (int p = 0; p < 4; ++p)
                C[p] = __builtin_amdgcn_mfma_f32_16x16x32_bf16(
                           A[p * 4 + t], B[t], C[p], 0, 0, 0);
        #pragma unroll
        for (int p = 0; p < 4; ++p)
            #pragma unroll
            for (int r = 0; r < 4; ++r) {
                const float s = (x2r[p * 4 + r] - 2.0f * C[p][r]) + e2c;
                bmin[p * 4 + r] = fminf(bmin[p * 4 + r], s);
            }
    }

    // reduce min across the 16 lanes of each quad-group (code dimension)
    #pragma unroll
    for (int i = 0; i < 16; ++i) {
        float v = bmin[i];
        v = fminf(v, __shfl_xor(v, 1));
        v = fminf(v, __shfl_xor(v, 2));
        v = fminf(v, __shfl_xor(v, 4));
        v = fminf(v, __shfl_xor(v, 8));
        bmin[i] = v;
    }
    if (mm == 0) {
        #pragma unroll
        for (int p = 0; p < 4; ++p)
            #pragma unroll
            for (int r = 0; r < 4; ++r)
                bfminw[wave][p * 16 + quad * 4 + r] = bmin[p * 4 + r];
    }
    __syncthreads();
    if (tid < 64) {
        const float mn = fminf(fminf(bfminw[0][tid], bfminw[1][tid]),
                               fminf(bfminw[2][tid], bfminw[3][tid]));
        const float M = 2.0e-4f * sqrtf(x2s[tid]) + 1.5e-4f;
        threshs[tid] = mn + 2.0f * M;
    }
    __syncthreads();   // after this barrier bfminw is dead; cand may be written

    float thr[16];
    #pragma unroll
    for (int p = 0; p < 4; ++p)
        #pragma unroll
        for (int r = 0; r < 4; ++r)
            thr[p * 4 + r] = threshs[p * 16 + quad * 4 + r];

    // ---- phase 2: recompute, collect candidates ----
    #pragma unroll 1
    for (int c = 0; c < 16; ++c) {
        short8 B[4];
        #pragma unroll
        for (int t = 0; t < 4; ++t)
            B[t] = *(const short8*)(bbase + (size_t)c * 16 * VQ_D + t * 32);
        const float e2c = e2g[c * 16];
        f32x4 C[4] = {{0.f,0.f,0.f,0.f},{0.f,0.f,0.f,0.f},
                      {0.f,0.f,0.f,0.f},{0.f,0.f,0.f,0.f}};
        #pragma unroll
        for (int t = 0; t < 4; ++t)
            #pragma unroll
            for (int p = 0; p < 4; ++p)
                C[p] = __builtin_amdgcn_mfma_f32_16x16x32_bf16(
                           A[p * 4 + t], B[t], C[p], 0, 0, 0);
        #pragma unroll
        for (int p = 0; p < 4; ++p)
            #pragma unroll
            for (int r = 0; r < 4; ++r) {
                const float s = (x2r[p * 4 + r] - 2.0f * C[p][r]) + e2c;
                if (s <= thr[p * 4 + r]) {
                    const int idx = atomicAdd(&ncand, 1);
                    if (idx < CAND_CAP) {
                        const int px   = p * 16 + quad * 4 + r;
                        const int code = wave * 256 + c * 16 + mm;
                        cand[idx] = ((unsigned)px << 16) | (unsigned)code;
                    }
                }
            }
    }
    __syncthreads();

    // ---- rescue: exact fp32 serial chain on candidates, one per lane ----
    const int nc = ncand < CAND_CAP ? ncand : CAND_CAP;
    for (int i = tid; i < nc; i += 256) {
        const unsigned pc = cand[i];
        const int px = (int)(pc >> 16);
        const int k  = (int)(pc & 0xFFFFu);
        const float* crow = cb + (size_t)k * VQ_D;
        float dot = 0.f;
        #pragma unroll
        for (int q = 0; q < 32; ++q) {
            const float4 cv = *(const float4*)(crow + q * 4);
            dot = fmaf(xl[(q * 4 + 0) * 64 + px], cv.x, dot);
            dot = fmaf(xl[(q * 4 + 1) * 64 + px], cv.y, dot);
            dot = fmaf(xl[(q * 4 + 2) * 64 + px], cv.z, dot);
            dot = fmaf(xl[(q * 4 + 3) * 64 + px], cv.w, dot);
        }
        const float t3 = (x2s[px] - 2.0f * dot) + e2[k];
        const unsigned long long key =
            ((unsigned long long)__float_as_uint(t3) << 32) | (unsigned)k;
        atomicMin(&fkey[px], key);
    }
    __syncthreads();

    // ---- writeback: vectorized codebook reads, nontemporal out stores ----
    {
        const int px = tid & 63;
        const int dh = tid >> 6;
        const int fb = (int)(fkey[px] & 0xFFFFFFFFULL);
        const float* crow = cb + (size_t)fb * VQ_D + dh * 32;
        float* og = out + (size_t)b * VQ_D * VQ_HW + hw0;
        #pragma unroll
        for (int j = 0; j < 8; ++j) {
            const float4 cv = *(const float4*)(crow + j * 4);
            const int d = dh * 32 + j * 4;
            __builtin_nontemporal_store(cv.x, &og[(size_t)(d + 0) * VQ_HW + px]);
            __builtin_nontemporal_store(cv.y, &og[(size_t)(d + 1) * VQ_HW + px]);
            __builtin_nontemporal_store(cv.z, &og[(size_t)(d + 2) * VQ_HW + px]);
            __builtin_nontemporal_store(cv.w, &og[(size_t)(d + 3) * VQ_HW + px]);
        }
    }
}

extern "C" void kernel_launch(void* const* d_in, const int* in_sizes, int n_in,
                              void* d_out, int out_size, void* d_ws, size_t ws_size,
                              hipStream_t stream) {
    const float* latents = (const float*)d_in[0];
    const float* cb      = (const float*)d_in[1];
    unsigned short* cbbf = (unsigned short*)d_ws;              // 256 KB
    float* e2            = (float*)((char*)d_ws + 262144);     // 4 KB
    float* out           = (float*)d_out;

    vq_prep_kernel<<<dim3(32), dim3(256), 0, stream>>>(cb, cbbf, e2);
    vq_main_kernel<<<dim3(1024), dim3(256), 0, stream>>>(latents, cb, cbbf, e2, out);
}